// Round 5
// baseline (380.569 us; speedup 1.0000x reference)
//
#include <hip/hip_runtime.h>

#define B_ROWS   16384
#define D_DIM    2048
#define L_LAYERS 6
#define THREADS  256                 // 4 waves/block
#define BLOCKS   512                 // exactly 2 blocks/CU resident, one generation
#define WPB      (THREADS / 64)
#define ROWS_PER_WAVE 8              // 512*4 waves * 8 rows = 16384

// Exact algebra: x_l = c_l*x0 + u_l, u_l = sum_{i<l} b_i,
//   c_{l+1} = c_l*(1 + x0.W_l) + u_l.W_l.
// Net = 6 dots/row + scalar recurrence + out = c*x0 + U.
//
// R4 post-mortem: 512-thr blocks pinned VGPR=128, 4x-unrolled dbuf body
// spilled to scratch (+327MB HBM writes). R5: 256-thr blocks with
// __launch_bounds__(256,2) -> 2 waves/SIMD -> 256-VGPR budget; ping-pong
// A/B row buffers in a ROLLED loop. Zero barriers in the row phase.
__global__ __launch_bounds__(THREADS, 2) void cross_net_kernel(
    const float* __restrict__ x,
    const float* __restrict__ W,
    const float* __restrict__ b,
    float* __restrict__ out)
{
    __shared__ float Wl[L_LAYERS][D_DIM];   // 48 KB
    __shared__ float Ul[D_DIM];             // 8 KB
    __shared__ float red[WPB][L_LAYERS];

    const int t    = threadIdx.x;
    const int lane = t & 63;
    const int wid  = t >> 6;

    // ---- setup: stage W, U = sum b_i, e[l] = (sum_{i<l} b_i).W_l ----
    {
        const int b0 = t * 4;               // 256 thr x 8 elems = 2048
        const int b1 = 1024 + t * 4;
        float pf[8] = {0.f,0.f,0.f,0.f,0.f,0.f,0.f,0.f};
        float e_red[L_LAYERS];
        #pragma unroll
        for (int l = 0; l < L_LAYERS; ++l) {
            const float4 w0 = *(const float4*)(W + l * D_DIM + b0);
            const float4 w1 = *(const float4*)(W + l * D_DIM + b1);
            const float4 v0 = *(const float4*)(b + l * D_DIM + b0);
            const float4 v1 = *(const float4*)(b + l * D_DIM + b1);
            e_red[l] = pf[0]*w0.x + pf[1]*w0.y + pf[2]*w0.z + pf[3]*w0.w
                     + pf[4]*w1.x + pf[5]*w1.y + pf[6]*w1.z + pf[7]*w1.w; // prefix BEFORE b_l
            pf[0]+=v0.x; pf[1]+=v0.y; pf[2]+=v0.z; pf[3]+=v0.w;
            pf[4]+=v1.x; pf[5]+=v1.y; pf[6]+=v1.z; pf[7]+=v1.w;
            *(float4*)&Wl[l][b0] = w0;
            *(float4*)&Wl[l][b1] = w1;
        }
        *(float4*)&Ul[b0] = make_float4(pf[0], pf[1], pf[2], pf[3]);
        *(float4*)&Ul[b1] = make_float4(pf[4], pf[5], pf[6], pf[7]);
        #pragma unroll
        for (int l = 0; l < L_LAYERS; ++l) {
            float v = e_red[l];
            #pragma unroll
            for (int off = 32; off >= 1; off >>= 1) v += __shfl_xor(v, off, 64);
            if (lane == 0) red[wid][l] = v;
        }
    }
    __syncthreads();                        // the ONLY barrier

    float e[L_LAYERS];
    #pragma unroll
    for (int l = 0; l < L_LAYERS; ++l) {
        float s = 0.f;
        #pragma unroll
        for (int w = 0; w < WPB; ++w) s += red[w][l];
        e[l] = s;
    }

    // ---- row phase: barrier-free, ping-pong pipelined, 8 rows/wave ----
    const int gw   = blockIdx.x * WPB + wid;           // 0..2047
    const float* xr  = x   + (size_t)(gw * ROWS_PER_WAVE) * D_DIM;
    float*       orw = out + (size_t)(gw * ROWS_PER_WAVE) * D_DIM;
    const int eoff = lane * 4;                         // + j*256, j=0..7

    float4 A[8], Bv[8];

    // macro-free helpers via lambdas (fully inlined, constant indices)
    auto load_row = [&](const float* p, float4 v[8]) {
        #pragma unroll
        for (int j = 0; j < 8; ++j) v[j] = *(const float4*)(p + j * 256 + eoff);
    };
    auto process_row = [&](const float4 v[8], float* op) {
        float p[L_LAYERS];
        #pragma unroll
        for (int l = 0; l < L_LAYERS; ++l) {
            float a = 0.f;
            #pragma unroll
            for (int j = 0; j < 8; ++j) {
                const float4 wv = *(const float4*)&Wl[l][j * 256 + eoff];
                a += v[j].x * wv.x + v[j].y * wv.y + v[j].z * wv.z + v[j].w * wv.w;
            }
            p[l] = a;
        }
        #pragma unroll
        for (int off = 32; off >= 1; off >>= 1) {
            #pragma unroll
            for (int l = 0; l < L_LAYERS; ++l) p[l] += __shfl_xor(p[l], off, 64);
        }
        float c = 1.f;
        #pragma unroll
        for (int l = 0; l < L_LAYERS; ++l) c = c * (1.f + p[l]) + e[l];
        #pragma unroll
        for (int j = 0; j < 8; ++j) {
            const float4 uv = *(const float4*)&Ul[j * 256 + eoff];
            float4 o;
            o.x = c * v[j].x + uv.x; o.y = c * v[j].y + uv.y;
            o.z = c * v[j].z + uv.z; o.w = c * v[j].w + uv.w;
            *(float4*)(op + j * 256 + eoff) = o;
        }
    };

    load_row(xr, A);                                   // row 0
    #pragma unroll 1
    for (int rr = 0; rr < ROWS_PER_WAVE / 2; ++rr) {
        load_row(xr + (size_t)(2 * rr + 1) * D_DIM, Bv);   // prefetch odd row
        process_row(A, orw + (size_t)(2 * rr) * D_DIM);    // compute/store even row
        if (rr < ROWS_PER_WAVE / 2 - 1)
            load_row(xr + (size_t)(2 * rr + 2) * D_DIM, A); // prefetch next even row
        process_row(Bv, orw + (size_t)(2 * rr + 1) * D_DIM);
    }
}

extern "C" void kernel_launch(void* const* d_in, const int* in_sizes, int n_in,
                              void* d_out, int out_size, void* d_ws, size_t ws_size,
                              hipStream_t stream) {
    (void)in_sizes; (void)n_in; (void)d_ws; (void)ws_size; (void)out_size;
    const float* x = (const float*)d_in[0];
    const float* W = (const float*)d_in[1];
    const float* b = (const float*)d_in[2];
    float* out = (float*)d_out;
    cross_net_kernel<<<dim3(BLOCKS), dim3(THREADS), 0, stream>>>(x, W, b, out);
}